// Round 1
// baseline (143.460 us; speedup 1.0000x reference)
//
#include <hip/hip_runtime.h>

// One 64-lane wave per target group; lane = filter index (F == 64 == wavefront).
// For each entry e in [spans[t], spans[t+1]): acc += sources[idx[e]*64 + lane].
// Coalesced 256B row reads, coalesced 256B output store, mean with max(count,1).

#define F 64

__global__ __launch_bounds__(256) void pool_mean_kernel(
    const float* __restrict__ sources,
    const int*   __restrict__ pooling_indices,
    const int*   __restrict__ pooling_spans,
    float*       __restrict__ out,
    int n_tgt)
{
    const int gtid    = blockIdx.x * blockDim.x + threadIdx.x;
    const int wave_id = gtid >> 6;           // one wave per target group
    const int lane    = threadIdx.x & 63;    // filter index

    if (wave_id >= n_tgt) return;

    const int e_beg = pooling_spans[wave_id];
    const int e_end = pooling_spans[wave_id + 1];

    float acc = 0.0f;
    for (int e = e_beg; e < e_end; ++e) {
        const int j = pooling_indices[e];            // uniform across wave -> broadcast
        acc += sources[(long long)j * F + lane];     // coalesced 256B row read
    }

    const int   cnt   = e_end - e_beg;
    const float denom = (cnt > 0) ? (float)cnt : 1.0f;
    out[(long long)wave_id * F + lane] = acc / denom;
}

extern "C" void kernel_launch(void* const* d_in, const int* in_sizes, int n_in,
                              void* d_out, int out_size, void* d_ws, size_t ws_size,
                              hipStream_t stream)
{
    const float* sources         = (const float*)d_in[0];
    const int*   pooling_indices = (const int*)d_in[1];
    const int*   pooling_spans   = (const int*)d_in[2];
    float*       out             = (float*)d_out;

    const int n_tgt = in_sizes[2] - 1;   // spans has N_TGT+1 entries

    const int threads = 256;                         // 4 waves per block
    const long long total_threads = (long long)n_tgt * 64;
    const int blocks = (int)((total_threads + threads - 1) / threads);

    pool_mean_kernel<<<blocks, threads, 0, stream>>>(
        sources, pooling_indices, pooling_spans, out, n_tgt);
}

// Round 2
// 76.387 us; speedup vs baseline: 1.8781x; 1.8781x over previous
//
#include <hip/hip_runtime.h>

// One 64-lane wave per target group (lane = filter, F == 64), persistent
// grid-stride over groups. Inner gather unrolled 8-deep with 4 independent
// accumulators: 8 index loads issue back-to-back, then 8 coalesced 256B row
// gathers are simultaneously in flight (2KB/wave MLP vs 256B before).

#define F 64

__global__ __launch_bounds__(256) void pool_mean_kernel(
    const float* __restrict__ sources,
    const int*   __restrict__ idx,
    const int*   __restrict__ spans,
    float*       __restrict__ out,
    int n_tgt)
{
    const int lane    = threadIdx.x & 63;
    const int wave0   = (blockIdx.x * blockDim.x + threadIdx.x) >> 6;
    const int n_waves = (gridDim.x * blockDim.x) >> 6;

    for (int t = wave0; t < n_tgt; t += n_waves) {
        const int e_beg = spans[t];
        const int e_end = spans[t + 1];

        float acc0 = 0.f, acc1 = 0.f, acc2 = 0.f, acc3 = 0.f;
        int e = e_beg;

        for (; e + 8 <= e_end; e += 8) {
            const int j0 = idx[e + 0], j1 = idx[e + 1], j2 = idx[e + 2], j3 = idx[e + 3];
            const int j4 = idx[e + 4], j5 = idx[e + 5], j6 = idx[e + 6], j7 = idx[e + 7];
            const float v0 = sources[(size_t)j0 * F + lane];
            const float v1 = sources[(size_t)j1 * F + lane];
            const float v2 = sources[(size_t)j2 * F + lane];
            const float v3 = sources[(size_t)j3 * F + lane];
            const float v4 = sources[(size_t)j4 * F + lane];
            const float v5 = sources[(size_t)j5 * F + lane];
            const float v6 = sources[(size_t)j6 * F + lane];
            const float v7 = sources[(size_t)j7 * F + lane];
            acc0 += v0; acc1 += v1; acc2 += v2; acc3 += v3;
            acc0 += v4; acc1 += v5; acc2 += v6; acc3 += v7;
        }
        for (; e + 4 <= e_end; e += 4) {
            const int j0 = idx[e + 0], j1 = idx[e + 1], j2 = idx[e + 2], j3 = idx[e + 3];
            const float v0 = sources[(size_t)j0 * F + lane];
            const float v1 = sources[(size_t)j1 * F + lane];
            const float v2 = sources[(size_t)j2 * F + lane];
            const float v3 = sources[(size_t)j3 * F + lane];
            acc0 += v0; acc1 += v1; acc2 += v2; acc3 += v3;
        }
        for (; e < e_end; ++e)
            acc0 += sources[(size_t)idx[e] * F + lane];

        const float acc = (acc0 + acc1) + (acc2 + acc3);
        const int   cnt = e_end - e_beg;
        out[(size_t)t * F + lane] = acc / (cnt > 0 ? (float)cnt : 1.0f);
    }
}

extern "C" void kernel_launch(void* const* d_in, const int* in_sizes, int n_in,
                              void* d_out, int out_size, void* d_ws, size_t ws_size,
                              hipStream_t stream)
{
    const float* sources         = (const float*)d_in[0];
    const int*   pooling_indices = (const int*)d_in[1];
    const int*   pooling_spans   = (const int*)d_in[2];
    float*       out             = (float*)d_out;

    const int n_tgt = in_sizes[2] - 1;   // spans has N_TGT+1 entries

    // Persistent: 2048 blocks x 256 threads = 8192 waves = 32 waves/CU * 256 CU.
    const int threads = 256;
    int blocks = 2048;
    const long long need = ((long long)n_tgt * 64 + threads - 1) / threads;
    if (need < blocks) blocks = (int)need;

    pool_mean_kernel<<<blocks, threads, 0, stream>>>(
        sources, pooling_indices, pooling_spans, out, n_tgt);
}

// Round 3
// 55.230 us; speedup vs baseline: 2.5975x; 1.3831x over previous
//
#include <hip/hip_runtime.h>

// 4 target groups per wave: each group owns a 16-lane sub-wave, lane handles
// 4 filters via float4 (16 lanes x 16B = 256B row, fully coalesced). One
// wave-wide gather instruction fetches 4 rows (1KB). 4-deep unroll with 4
// independent float4 accumulators keeps 4 gathers in flight per sub-group.

__global__ __launch_bounds__(256) void pool_mean_kernel(
    const float4* __restrict__ src4,    // sources viewed as [N_SRC][16] float4
    const int*    __restrict__ idx,
    const int*    __restrict__ spans,
    float4*       __restrict__ out4,    // out viewed as [N_TGT][16] float4
    int n_tgt)
{
    const int tid = blockIdx.x * blockDim.x + threadIdx.x;
    const int t   = tid >> 4;            // target group = one 16-lane sub-wave
    const int l   = threadIdx.x & 15;    // float4 slot within the row
    if (t >= n_tgt) return;

    const int e_beg = spans[t];
    const int e_end = spans[t + 1];

    float4 a0 = make_float4(0.f,0.f,0.f,0.f);
    float4 a1 = make_float4(0.f,0.f,0.f,0.f);
    float4 a2 = make_float4(0.f,0.f,0.f,0.f);
    float4 a3 = make_float4(0.f,0.f,0.f,0.f);

    int e = e_beg;
    for (; e + 4 <= e_end; e += 4) {
        const int j0 = idx[e + 0];
        const int j1 = idx[e + 1];
        const int j2 = idx[e + 2];
        const int j3 = idx[e + 3];
        const float4 v0 = src4[(size_t)j0 * 16 + l];
        const float4 v1 = src4[(size_t)j1 * 16 + l];
        const float4 v2 = src4[(size_t)j2 * 16 + l];
        const float4 v3 = src4[(size_t)j3 * 16 + l];
        a0.x += v0.x; a0.y += v0.y; a0.z += v0.z; a0.w += v0.w;
        a1.x += v1.x; a1.y += v1.y; a1.z += v1.z; a1.w += v1.w;
        a2.x += v2.x; a2.y += v2.y; a2.z += v2.z; a2.w += v2.w;
        a3.x += v3.x; a3.y += v3.y; a3.z += v3.z; a3.w += v3.w;
    }
    if (e + 2 <= e_end) {
        const int j0 = idx[e + 0];
        const int j1 = idx[e + 1];
        const float4 v0 = src4[(size_t)j0 * 16 + l];
        const float4 v1 = src4[(size_t)j1 * 16 + l];
        a0.x += v0.x; a0.y += v0.y; a0.z += v0.z; a0.w += v0.w;
        a1.x += v1.x; a1.y += v1.y; a1.z += v1.z; a1.w += v1.w;
        e += 2;
    }
    if (e < e_end) {
        const int j = idx[e];
        const float4 v = src4[(size_t)j * 16 + l];
        a2.x += v.x; a2.y += v.y; a2.z += v.z; a2.w += v.w;
    }

    float4 s;
    s.x = (a0.x + a1.x) + (a2.x + a3.x);
    s.y = (a0.y + a1.y) + (a2.y + a3.y);
    s.z = (a0.z + a1.z) + (a2.z + a3.z);
    s.w = (a0.w + a1.w) + (a2.w + a3.w);

    const int   cnt = e_end - e_beg;
    const float inv = 1.0f / (float)(cnt > 0 ? cnt : 1);
    s.x *= inv; s.y *= inv; s.z *= inv; s.w *= inv;

    out4[(size_t)t * 16 + l] = s;
}

extern "C" void kernel_launch(void* const* d_in, const int* in_sizes, int n_in,
                              void* d_out, int out_size, void* d_ws, size_t ws_size,
                              hipStream_t stream)
{
    const float4* src4            = (const float4*)d_in[0];
    const int*    pooling_indices = (const int*)d_in[1];
    const int*    pooling_spans   = (const int*)d_in[2];
    float4*       out4            = (float4*)d_out;

    const int n_tgt = in_sizes[2] - 1;   // spans has N_TGT+1 entries

    const int threads = 256;             // 16 groups per block (4 per wave)
    const long long total_threads = (long long)n_tgt * 16;
    const int blocks = (int)((total_threads + threads - 1) / threads);

    pool_mean_kernel<<<blocks, threads, 0, stream>>>(
        src4, pooling_indices, pooling_spans, out4, n_tgt);
}

// Round 5
// 51.934 us; speedup vs baseline: 2.7623x; 1.0634x over previous
//
#include <hip/hip_runtime.h>

// 4 target groups per wave, 16-lane sub-groups, float4 per lane (256B/row).
// Whole group processed in 8-wide predicated batches: all 8 idx loads and all
// 8 row gathers issue unconditionally (index clamped to last valid entry so
// out-of-range lanes re-read a cached line), adds are masked. 86% of groups
// (len<=8) finish in one fully-MLP batch. Output uses non-temporal stores to
// avoid evicting sources (256MB == L3 size) from Infinity Cache.

typedef float floatx4 __attribute__((ext_vector_type(4)));

__global__ __launch_bounds__(256) void pool_mean_kernel(
    const float4* __restrict__ src4,    // sources as [N_SRC][16] float4
    const int*    __restrict__ idx,
    const int*    __restrict__ spans,
    float4*       __restrict__ out4,    // out as [N_TGT][16] float4
    int n_tgt)
{
    const int tid = blockIdx.x * blockDim.x + threadIdx.x;
    const int t   = tid >> 4;            // target group = one 16-lane sub-wave
    const int l   = threadIdx.x & 15;    // float4 slot within the row
    if (t >= n_tgt) return;

    const int e_beg = spans[t];
    const int e_end = spans[t + 1];
    const int last  = e_end - 1;         // valid whenever the loop body runs

    float4 a0 = make_float4(0.f,0.f,0.f,0.f);
    float4 a1 = make_float4(0.f,0.f,0.f,0.f);
    float4 a2 = make_float4(0.f,0.f,0.f,0.f);
    float4 a3 = make_float4(0.f,0.f,0.f,0.f);

    for (int e = e_beg; e < e_end; e += 8) {
        const int r = e_end - e;         // entries remaining (>0)

        const int e1 = e + 1 <= last ? e + 1 : last;
        const int e2 = e + 2 <= last ? e + 2 : last;
        const int e3 = e + 3 <= last ? e + 3 : last;
        const int e4 = e + 4 <= last ? e + 4 : last;
        const int e5 = e + 5 <= last ? e + 5 : last;
        const int e6 = e + 6 <= last ? e + 6 : last;
        const int e7 = e + 7 <= last ? e + 7 : last;

        const int j0 = idx[e];
        const int j1 = idx[e1];
        const int j2 = idx[e2];
        const int j3 = idx[e3];
        const int j4 = idx[e4];
        const int j5 = idx[e5];
        const int j6 = idx[e6];
        const int j7 = idx[e7];

        const float4 v0 = src4[(size_t)j0 * 16 + l];
        const float4 v1 = src4[(size_t)j1 * 16 + l];
        const float4 v2 = src4[(size_t)j2 * 16 + l];
        const float4 v3 = src4[(size_t)j3 * 16 + l];
        const float4 v4 = src4[(size_t)j4 * 16 + l];
        const float4 v5 = src4[(size_t)j5 * 16 + l];
        const float4 v6 = src4[(size_t)j6 * 16 + l];
        const float4 v7 = src4[(size_t)j7 * 16 + l];

        const float m1 = (r > 1) ? 1.f : 0.f;
        const float m2 = (r > 2) ? 1.f : 0.f;
        const float m3 = (r > 3) ? 1.f : 0.f;
        const float m4 = (r > 4) ? 1.f : 0.f;
        const float m5 = (r > 5) ? 1.f : 0.f;
        const float m6 = (r > 6) ? 1.f : 0.f;
        const float m7 = (r > 7) ? 1.f : 0.f;

        a0.x += v0.x;            a0.y += v0.y;            a0.z += v0.z;            a0.w += v0.w;
        a1.x = fmaf(m1, v1.x, a1.x); a1.y = fmaf(m1, v1.y, a1.y); a1.z = fmaf(m1, v1.z, a1.z); a1.w = fmaf(m1, v1.w, a1.w);
        a2.x = fmaf(m2, v2.x, a2.x); a2.y = fmaf(m2, v2.y, a2.y); a2.z = fmaf(m2, v2.z, a2.z); a2.w = fmaf(m2, v2.w, a2.w);
        a3.x = fmaf(m3, v3.x, a3.x); a3.y = fmaf(m3, v3.y, a3.y); a3.z = fmaf(m3, v3.z, a3.z); a3.w = fmaf(m3, v3.w, a3.w);
        a0.x = fmaf(m4, v4.x, a0.x); a0.y = fmaf(m4, v4.y, a0.y); a0.z = fmaf(m4, v4.z, a0.z); a0.w = fmaf(m4, v4.w, a0.w);
        a1.x = fmaf(m5, v5.x, a1.x); a1.y = fmaf(m5, v5.y, a1.y); a1.z = fmaf(m5, v5.z, a1.z); a1.w = fmaf(m5, v5.w, a1.w);
        a2.x = fmaf(m6, v6.x, a2.x); a2.y = fmaf(m6, v6.y, a2.y); a2.z = fmaf(m6, v6.z, a2.z); a2.w = fmaf(m6, v6.w, a2.w);
        a3.x = fmaf(m7, v7.x, a3.x); a3.y = fmaf(m7, v7.y, a3.y); a3.z = fmaf(m7, v7.z, a3.z); a3.w = fmaf(m7, v7.w, a3.w);
    }

    float4 s;
    s.x = (a0.x + a1.x) + (a2.x + a3.x);
    s.y = (a0.y + a1.y) + (a2.y + a3.y);
    s.z = (a0.z + a1.z) + (a2.z + a3.z);
    s.w = (a0.w + a1.w) + (a2.w + a3.w);

    const int   cnt = e_end - e_beg;
    const float inv = 1.0f / (float)(cnt > 0 ? cnt : 1);
    s.x *= inv; s.y *= inv; s.z *= inv; s.w *= inv;

    floatx4 sv;
    sv.x = s.x; sv.y = s.y; sv.z = s.z; sv.w = s.w;
    __builtin_nontemporal_store(sv, (floatx4*)&out4[(size_t)t * 16 + l]);
}

extern "C" void kernel_launch(void* const* d_in, const int* in_sizes, int n_in,
                              void* d_out, int out_size, void* d_ws, size_t ws_size,
                              hipStream_t stream)
{
    const float4* src4            = (const float4*)d_in[0];
    const int*    pooling_indices = (const int*)d_in[1];
    const int*    pooling_spans   = (const int*)d_in[2];
    float4*       out4            = (float4*)d_out;

    const int n_tgt = in_sizes[2] - 1;   // spans has N_TGT+1 entries

    const int threads = 256;             // 16 groups per block (4 per wave)
    const long long total_threads = (long long)n_tgt * 16;
    const int blocks = (int)((total_threads + threads - 1) / threads);

    pool_mean_kernel<<<blocks, threads, 0, stream>>>(
        src4, pooling_indices, pooling_spans, out4, n_tgt);
}